// Round 4
// baseline (292.478 us; speedup 1.0000x reference)
//
#include <hip/hip_runtime.h>
#include <hip/hip_bf16.h>

typedef __attribute__((ext_vector_type(8))) short bf16x8;
typedef __attribute__((ext_vector_type(4))) float f32x4;

#define DIN 24
#define DOUT 47
#define SPD (DOUT*DOUT)
#define CIN 32
#define COUT 64
#define SP_IN 13824
#define SP_OUT 103823
#define GROUPS 8
#define WPK_OFF 512
#define LROW 40          // elems per (plane,iw) row: 32 ci + 8 pad (80B, 16B-aligned)
#define PLANE 1000       // 25 rows * LROW  (iw 0..23 data, iw=24 zero row)

__device__ __forceinline__ unsigned short f2bf(float v) {
    __hip_bfloat16 h = __float2bfloat16(v);
    return *(const unsigned short*)&h;
}

__device__ __forceinline__ float hswish(float z) {
    float c = fminf(fmaxf(z + 3.f, 0.f), 6.f);
    return z * c * (1.f / 6.f);
}

// wpk[tap][coblk][lane][j]: A-frag bf16, co = coblk*16+(lane&15), ci = (lane>>4)*8+j
__global__ __launch_bounds__(256)
void repack_w(const float* __restrict__ w, unsigned short* __restrict__ wpk)
{
    int i = blockIdx.x * 256 + threadIdx.x;
    if (i >= 27 * 4 * 64 * 8) return;
    int j = i & 7;
    int lane = (i >> 3) & 63;
    int coblk = (i >> 9) & 3;
    int tap = i >> 11;
    int kw = tap % 3, kh = (tap / 3) % 3, kd = tap / 9;
    int co = coblk * 16 + (lane & 15);
    int ci = (lane >> 4) * 8 + j;
    wpk[i] = f2bf(w[(((co * CIN + ci) * 3 + kd) * 3 + kh) * 3 + kw]);
}

// One parity class: columns = (2 oh of parity OHP) x (8 ow of parity OWP).
// NKD=1 -> even od (kd=1, idl=0); NKD=2 -> odd od (kd=0 idl=1, kd=2 idl=0).
template<int NKD, int OHP, int OWP>
__device__ __forceinline__ void cls_pass(
    const unsigned short* __restrict__ wb,
    const unsigned short* __restrict__ xs,
    int poff, const int (&iwo)[3][2],
    int od, int h0, int owi, int ohsel,
    const f32x4& bv, float* __restrict__ yb,
    float& s1, float& s2)
{
    f32x4 acc[2][3];
    #pragma unroll
    for (int k2 = 0; k2 < 2; ++k2)
        #pragma unroll
        for (int w = 0; w < 3; ++w) acc[k2][w] = (f32x4){0.f, 0.f, 0.f, 0.f};

    #pragma unroll
    for (int dk = 0; dk < NKD; ++dk) {
        const int kd  = (NKD == 1) ? 1 : (dk ? 2 : 0);
        const int idl = (NKD == 1) ? 0 : (dk ? 0 : 1);
        #pragma unroll
        for (int khi = 0; khi < (OHP ? 2 : 1); ++khi) {
            const int kh = OHP ? (khi ? 2 : 0) : 1;
            const int ihb = (OHP + 1 - kh) >> 1;        // 0 or 1
            #pragma unroll
            for (int kwi = 0; kwi < (OWP ? 2 : 1); ++kwi) {
                const int kw = OWP ? (kwi ? 2 : 0) : 1;
                const int sh = (OWP && kw == 0) ? 1 : 0;
                const int tap = (kd * 3 + kh) * 3 + kw;
                const bf16x8 af = *(const bf16x8*)&wb[tap * 2048];
                #pragma unroll
                for (int k2 = 0; k2 < 2; ++k2) {
                    const int pbase = (idl * 5 + ihb + 2 * k2) * PLANE;
                    #pragma unroll
                    for (int w = 0; w < 3; ++w) {
                        const bf16x8 b = *(const bf16x8*)&xs[pbase + poff + iwo[w][sh]];
                        acc[k2][w] = __builtin_amdgcn_mfma_f32_16x16x32_bf16(af, b, acc[k2][w], 0, 0, 0);
                    }
                }
            }
        }
    }

    #pragma unroll
    for (int k2 = 0; k2 < 2; ++k2) {
        const int oh = h0 + OHP + 4 * k2 + 2 * ohsel;
        #pragma unroll
        for (int w = 0; w < 3; ++w) {
            const int ow = 16 * w + 2 * owi + OWP;
            const bool v = (oh < DOUT) && (ow < DOUT);
            const size_t sp = (size_t)od * SPD + oh * DOUT + ow;
            #pragma unroll
            for (int j = 0; j < 4; ++j) {
                float val = acc[k2][w][j] + bv[j];
                float sw = val / (1.f + __expf(-val));
                if (v) { yb[j * SP_OUT + sp] = sw; s1 += sw; s2 += sw * sw; }
            }
        }
    }
}

__global__ __launch_bounds__(256, 4)
void conv_mfma(const float* __restrict__ x, const unsigned short* __restrict__ wpk,
               const float* __restrict__ bias, float* __restrict__ y,
               float* __restrict__ stats)
{
    __shared__ unsigned short xs[10 * PLANE];   // 20000 B

    const int bx = blockIdx.x;                  // 24 od-pairs * 6 oh-slabs
    const int u = bx / 6;                       // od pair (2u, 2u+1)
    const int s = bx - u * 6;                   // oh slab [8s, 8s+8)
    const int n = blockIdx.z;
    const int tid = threadIdx.x;

    // ---- stage 10 planes (idl 0..1, ihl 0..4) x 24 iw x 32 ci, fp32->bf16 transpose
    const float* xb = x + (size_t)n * (CIN * SP_IN);
    for (int i = tid; i < 1920; i += 256) {     // 480 rows * 6 float4 / (od-pair: 10 planes)
        int j = i % 6;
        int r = i / 6;
        int ci = r & 31;
        int pl = r >> 5;                        // 0..9
        int ihl = pl % 5, idl = pl / 5;
        int id = min(u + idl, 23);
        int ih = min(4 * s + ihl, 23);
        const float4 v = *(const float4*)(xb + ci * SP_IN + (id * DIN + ih) * DIN + 4 * j);
        int base = pl * PLANE + (4 * j) * LROW + ci;
        xs[base + 0 * LROW] = f2bf(v.x);
        xs[base + 1 * LROW] = f2bf(v.y);
        xs[base + 2 * LROW] = f2bf(v.z);
        xs[base + 3 * LROW] = f2bf(v.w);
    }
    for (int i = tid; i < 320; i += 256) {      // zero row iw=24 per plane
        int ci = i & 31, pl = i >> 5;
        xs[pl * PLANE + 24 * LROW + ci] = 0;
    }
    __syncthreads();

    const int lane = tid & 63;
    const int cb = tid >> 6;                    // wave -> co block (16 co)
    const int owi = lane & 7;                   // ow index within tile (stride 2)
    const int ohsel = (lane >> 3) & 1;          // which oh of the pair
    const int kg = lane >> 4;                   // k-group (8 ci)
    const int poff = ohsel * PLANE;

    int iwo[3][2];
    #pragma unroll
    for (int w = 0; w < 3; ++w) {
        iwo[w][0] = (8 * w + owi) * LROW + kg * 8;
        iwo[w][1] = iwo[w][0] + LROW;
    }

    const unsigned short* wb = wpk + (size_t)cb * 512 + (size_t)lane * 8;  // + tap*2048
    const f32x4 bv = *(const f32x4*)&bias[cb * 16 + kg * 4];
    float* yb = y + ((size_t)n * COUT + cb * 16 + kg * 4) * SP_OUT;
    float s1 = 0.f, s2 = 0.f;
    const int od0 = 2 * u;
    const int h0 = 8 * s;

    cls_pass<1, 0, 0>(wb, xs, poff, iwo, od0, h0, owi, ohsel, bv, yb, s1, s2);
    cls_pass<1, 0, 1>(wb, xs, poff, iwo, od0, h0, owi, ohsel, bv, yb, s1, s2);
    cls_pass<1, 1, 0>(wb, xs, poff, iwo, od0, h0, owi, ohsel, bv, yb, s1, s2);
    cls_pass<1, 1, 1>(wb, xs, poff, iwo, od0, h0, owi, ohsel, bv, yb, s1, s2);
    if (od0 + 1 < DOUT) {
        cls_pass<2, 0, 0>(wb, xs, poff, iwo, od0 + 1, h0, owi, ohsel, bv, yb, s1, s2);
        cls_pass<2, 0, 1>(wb, xs, poff, iwo, od0 + 1, h0, owi, ohsel, bv, yb, s1, s2);
        cls_pass<2, 1, 0>(wb, xs, poff, iwo, od0 + 1, h0, owi, ohsel, bv, yb, s1, s2);
        cls_pass<2, 1, 1>(wb, xs, poff, iwo, od0 + 1, h0, owi, ohsel, bv, yb, s1, s2);
    }

    // stats: rows kg<2 -> group 2cb, kg>=2 -> 2cb+1 (halves at lane 32 boundary)
    #pragma unroll
    for (int off = 16; off; off >>= 1) {
        s1 += __shfl_down(s1, off);
        s2 += __shfl_down(s2, off);
    }
    if ((lane & 31) == 0) {
        const int g = cb * 2 + (lane >> 5);
        atomicAdd(&stats[(n * GROUPS + g) * 2 + 0], s1);
        atomicAdd(&stats[(n * GROUPS + g) * 2 + 1], s2);
    }
}

__global__ __launch_bounds__(256)
void norm_hswish(float* __restrict__ y, const float* __restrict__ stats)
{
    const int total4 = (8 * COUT * SP_OUT) / 4;
    const int grp4 = (8 * SP_OUT) / 4;
    const float inv_cnt = 1.0f / (8.0f * (float)SP_OUT);
    float4* p = (float4*)y;
    int idx = blockIdx.x * 256 + threadIdx.x;
    const int stride = gridDim.x * 256;
    for (int i = idx; i < total4; i += stride) {
        const int ng = i / grp4;
        const float m1 = stats[ng * 2 + 0] * inv_cnt;
        const float m2 = stats[ng * 2 + 1] * inv_cnt;
        const float var = m2 - m1 * m1;
        const float rstd = rsqrtf(var + 1e-5f);
        float4 v = p[i];
        v.x = hswish((v.x - m1) * rstd);
        v.y = hswish((v.y - m1) * rstd);
        v.z = hswish((v.z - m1) * rstd);
        v.w = hswish((v.w - m1) * rstd);
        p[i] = v;
    }
}

extern "C" void kernel_launch(void* const* d_in, const int* in_sizes, int n_in,
                              void* d_out, int out_size, void* d_ws, size_t ws_size,
                              hipStream_t stream)
{
    const float* x    = (const float*)d_in[0];
    const float* w    = (const float*)d_in[1];
    const float* bias = (const float*)d_in[2];
    float* y     = (float*)d_out;
    float* stats = (float*)d_ws;
    unsigned short* wpk = (unsigned short*)((char*)d_ws + WPK_OFF);

    hipMemsetAsync(d_ws, 0, 512, stream);
    repack_w<<<216, 256, 0, stream>>>(w, wpk);

    dim3 grid(24 * 6, 1, 8);
    conv_mfma<<<grid, 256, 0, stream>>>(x, wpk, bias, y, stats);

    norm_hswish<<<2048, 256, 0, stream>>>(y, stats);
}